// Round 1
// baseline (1617.508 us; speedup 1.0000x reference)
//
#include <hip/hip_runtime.h>
#include <math.h>

// BNAF layer: B=256, W=64, I=64, O=64, W_IN=128. M = B*W = 16384 rows.
// d_out: [output (16384*64) | logj_out (16384*64)] fp32.
//
// ws layout (floats):
//   W2T  [256][4096]  @ 0          (transpose of w_w2 [4096][256])
//   W1T  [128][256]   @ 1048576    (transpose of w_w1)
//   B1T  [128][256]   @ 1081344    (transpose of b_w1)
//   BW2T [256][64]    @ 1114112    (transpose of b_w2)
//   Hw   [16384][256] @ 1130496    (tanh hypernet activations, w-net)
//   Hb   [16384][256] @ 5324800    (b-net)
// total 9,519,104 floats = 36.3 MB

#define M_TOTAL 16384
#define OUT_HALF 1048576  // 16384*64

// ---------------- K0: weight transposes (LDS 64x64 tiles) ----------------
__global__ __launch_bounds__(256) void k_transpose(
    const float* __restrict__ w_w2, const float* __restrict__ w_w1,
    const float* __restrict__ b_w1, const float* __restrict__ b_w2,
    float* __restrict__ W2T, float* __restrict__ W1T,
    float* __restrict__ B1T, float* __restrict__ BW2T) {
  __shared__ float tile[64][65];
  int b = blockIdx.x;
  const float* src; float* dst; int R, C, rt, ct;
  if (b < 256)      { src = w_w2; dst = W2T;  R = 4096; C = 256; rt = b >> 2;        ct = b & 3; }
  else if (b < 264) { src = w_w1; dst = W1T;  R = 256;  C = 128; rt = (b-256) >> 1;  ct = (b-256) & 1; }
  else if (b < 272) { src = b_w1; dst = B1T;  R = 256;  C = 128; rt = (b-264) >> 1;  ct = (b-264) & 1; }
  else              { src = b_w2; dst = BW2T; R = 64;   C = 256; rt = 0;             ct = b - 272; }
  int r0 = rt * 64, c0 = ct * 64;
  int lane = threadIdx.x & 63, q = threadIdx.x >> 6;
  #pragma unroll
  for (int rr = 0; rr < 16; ++rr) {
    int rl = q * 16 + rr;
    tile[rl][lane] = src[(r0 + rl) * C + c0 + lane];
  }
  __syncthreads();
  #pragma unroll
  for (int rr = 0; rr < 16; ++rr) {
    int cl = q * 16 + rr;
    dst[(c0 + cl) * R + r0 + lane] = tile[lane][cl];  // stride-65 LDS read: conflict-free
  }
}

// ---------------- K1: hypernets -> Hw, Hb ----------------
// grid 512 x 256 threads. lane = h (within 64-group), wave og picks 8 m-rows.
// Embedding rows are wave-uniform -> s_load; W1T/B1T loads + H stores coalesced.
__global__ __launch_bounds__(256) void k_hyper(
    const float* __restrict__ emb,
    const float* __restrict__ W1T, const float* __restrict__ w_b1,
    const float* __restrict__ B1T, const float* __restrict__ b_b1,
    float* __restrict__ Hw, float* __restrict__ Hb) {
  int t = threadIdx.x;
  int lane = t & 63;
  int og = __builtin_amdgcn_readfirstlane(t >> 6);  // 0..3, wave-uniform
  int m0 = blockIdx.x * 32 + og * 8;                // 8 rows per thread

  for (int net = 0; net < 2; ++net) {
    const float* WT   = net ? B1T  : W1T;
    const float* bias = net ? b_b1 : w_b1;
    float*       H    = net ? Hb   : Hw;
    for (int hg = 0; hg < 4; ++hg) {
      int h = hg * 64 + lane;
      float bv = bias[h];  // coalesced vector load
      float acc[8];
      #pragma unroll
      for (int mm = 0; mm < 8; ++mm) acc[mm] = 0.f;
      for (int ec = 0; ec < 16; ++ec) {  // e in chunks of 8
        float wv[8];
        #pragma unroll
        for (int j = 0; j < 8; ++j) wv[j] = WT[(ec * 8 + j) * 256 + hg * 64 + lane];
        #pragma unroll
        for (int mm = 0; mm < 8; ++mm) {
          const float* Erow = emb + (m0 + mm) * 128 + ec * 8;  // uniform -> s_load
          #pragma unroll
          for (int j = 0; j < 8; ++j) acc[mm] = fmaf(Erow[j], wv[j], acc[mm]);
        }
      }
      #pragma unroll
      for (int mm = 0; mm < 8; ++mm)
        H[(m0 + mm) * 256 + h] = tanhf(acc[mm] + bv);  // coalesced store
    }
  }
}

// ---------------- K2: fused main GEMM + exp-contraction + logsumexp ----------------
// grid 512 x 256 threads. lane = o (64), wave og picks 8 m-rows (32 m per block).
// Per h-chunk of 16: 16 coalesced w2t vector loads (reused across 8 rows) +
// per-row s_load_dwordx16 of Hw + 128 v_fmac_f32 (SGPR operand). No LDS, no barriers.
__global__ __launch_bounds__(256) void k_main(
    const float* __restrict__ input, const float* __restrict__ logj,
    const float* __restrict__ W2T, const float* __restrict__ w_b2,
    const float* __restrict__ BW2T, const float* __restrict__ b_b2,
    const float* __restrict__ Hw, const float* __restrict__ Hb,
    float* __restrict__ out) {
  int t = threadIdx.x;
  int o = t & 63;
  int og = __builtin_amdgcn_readfirstlane(t >> 6);  // 0..3
  int m0 = blockIdx.x * 32 + og * 8;

  // ---- phase 1: b1[m][o] = b_w2 @ h_b + b_b2 -> init output accumulators ----
  float outa[8];
  {
    float bb = b_b2[o];
    #pragma unroll
    for (int c = 0; c < 8; ++c) outa[c] = bb;
  }
  for (int hc = 0; hc < 16; ++hc) {
    float wv[16];
    #pragma unroll
    for (int j = 0; j < 16; ++j) wv[j] = BW2T[(hc * 16 + j) * 64 + o];
    #pragma unroll
    for (int c = 0; c < 8; ++c) {
      const float* Hrow = Hb + (m0 + c) * 256 + hc * 16;  // uniform -> s_load_dwordx16
      #pragma unroll
      for (int j = 0; j < 16; ++j) outa[c] = fmaf(Hrow[j], wv[j], outa[c]);
    }
  }

  // ---- phase 2: i-loop — G = w1[m, i, :], fused exp-contract + online LSE ----
  float mx[8], sm[8];
  #pragma unroll
  for (int c = 0; c < 8; ++c) { mx[c] = -INFINITY; sm[c] = 0.f; }

  for (int i = 0; i < 64; ++i) {
    float G[8];
    {
      float wbv = w_b2[i * 64 + o];  // coalesced vector load
      #pragma unroll
      for (int c = 0; c < 8; ++c) G[c] = wbv;
    }
    for (int hc = 0; hc < 16; ++hc) {
      float wv[16];
      #pragma unroll
      for (int j = 0; j < 16; ++j) wv[j] = W2T[(hc * 16 + j) * 4096 + i * 64 + o];
      #pragma unroll
      for (int c = 0; c < 8; ++c) {
        const float* Hrow = Hw + (m0 + c) * 256 + hc * 16;  // uniform -> s_load_dwordx16
        #pragma unroll
        for (int j = 0; j < 16; ++j) G[c] = fmaf(Hrow[j], wv[j], G[c]);
      }
    }
    #pragma unroll
    for (int c = 0; c < 8; ++c) {
      float xin = input[(m0 + c) * 64 + i];  // uniform -> s_load
      float lj  = logj [(m0 + c) * 64 + i];
      float g = G[c];
      outa[c] = fmaf(xin, __expf(g), outa[c]);
      float v  = g + lj;
      float nm = fmaxf(mx[c], v);
      sm[c] = fmaf(sm[c], __expf(mx[c] - nm), __expf(v - nm));
      mx[c] = nm;
    }
  }

  // ---- store (coalesced along o) ----
  #pragma unroll
  for (int c = 0; c < 8; ++c) {
    int row = (m0 + c) * 64;
    out[row + o] = outa[c];
    out[OUT_HALF + row + o] = mx[c] + __logf(sm[c]);
  }
}

extern "C" void kernel_launch(void* const* d_in, const int* in_sizes, int n_in,
                              void* d_out, int out_size, void* d_ws, size_t ws_size,
                              hipStream_t stream) {
  const float* input = (const float*)d_in[0];
  const float* w_emb = (const float*)d_in[1];
  const float* logj  = (const float*)d_in[2];
  const float* w_w1  = (const float*)d_in[3];
  const float* w_b1  = (const float*)d_in[4];
  const float* w_w2  = (const float*)d_in[5];
  const float* w_b2  = (const float*)d_in[6];
  const float* b_w1  = (const float*)d_in[7];
  const float* b_b1  = (const float*)d_in[8];
  const float* b_w2  = (const float*)d_in[9];
  const float* b_b2  = (const float*)d_in[10];
  float* out = (float*)d_out;

  float* ws   = (float*)d_ws;
  float* W2T  = ws;               // 1,048,576
  float* W1T  = W2T + 1048576;    // 32,768
  float* B1T  = W1T + 32768;      // 32,768
  float* BW2T = B1T + 32768;      // 16,384
  float* Hw   = BW2T + 16384;     // 4,194,304
  float* Hb   = Hw + 4194304;     // 4,194,304

  hipLaunchKernelGGL(k_transpose, dim3(276), dim3(256), 0, stream,
                     w_w2, w_w1, b_w1, b_w2, W2T, W1T, B1T, BW2T);
  hipLaunchKernelGGL(k_hyper, dim3(512), dim3(256), 0, stream,
                     w_emb, W1T, w_b1, B1T, b_b1, Hw, Hb);
  hipLaunchKernelGGL(k_main, dim3(512), dim3(256), 0, stream,
                     input, logj, W2T, w_b2, BW2T, b_b2, Hw, Hb, out);
}

// Round 2
// 239.712 us; speedup vs baseline: 6.7477x; 6.7477x over previous
//
#include <hip/hip_runtime.h>
#include <math.h>

// BNAF layer via MFMA. B=256, W=64, I=O=64, W_IN=128. M = B*W = 16384.
// Main GEMM: C[m, i*64+o] = Hw[16384,256] @ W2T[256,4096]  (34.4 GFLOP, bf16 MFMA)
// d_out: [output (16384*64) | logj_out (16384*64)] fp32.
//
// ws layout (bytes):
//   W2F  @ 0          2,097,152  bf16, MFMA-B-frag-swizzled w_w2
//   W1F  @ 2,097,152    131,072  bf16, swizzled concat(w_w1,b_w1) as B [128k x 512n]
//   BW2F @ 2,228,224     32,768  bf16, swizzled b_w2 as B [256k x 64n]
//   Hcat @ 2,260,992 16,777,216  bf16 [16384][512]: cols 0-255 = Hw, 256-511 = Hb
//   P    @ 19,038,208 16,777,216 fp32 partials: [outa half0|half1 | se half0|half1] x 1M
// total 35,815,424 B (fits: previous round used 36.3 MB of ws successfully)

typedef __attribute__((ext_vector_type(8))) short s16x8;   // 8 bf16 = 4 VGPR (MFMA A/B frag)
typedef __attribute__((ext_vector_type(4))) float f32x4;   // MFMA C/D frag

__device__ inline unsigned short f2bf(float f) {           // fp32 -> bf16 RNE
  unsigned int u = __float_as_uint(f);
  u += 0x7fffu + ((u >> 16) & 1u);
  return (unsigned short)(u >> 16);
}

__device__ inline s16x8 cvt8(float4 a, float4 b) {
  s16x8 v;
  v[0] = (short)f2bf(a.x); v[1] = (short)f2bf(a.y); v[2] = (short)f2bf(a.z); v[3] = (short)f2bf(a.w);
  v[4] = (short)f2bf(b.x); v[5] = (short)f2bf(b.y); v[6] = (short)f2bf(b.z); v[7] = (short)f2bf(b.w);
  return v;
}

// ---------------- K0: pre-swizzle weights into MFMA B-fragment layouts (bf16) ----------------
// 16x16x32 B frag [32k x 16n]: lane l holds n = l&15, k = (l>>4)*8 + e, e=0..7 (16B/lane).
// W2F  chunk c = i*2048 + ks*256 + ot*64 + l  (i<64, ks<8, ot<4)  <- w_w2[(i*64+ot*16+(l&15))*256 + ks*32+(l>>4)*8]
// W1F  chunk c = ks*2048 + nt*64 + l          (ks<4, nt<32)       <- {w_w1|b_w1}[n][k], n = nt*16+(l&15)
// BW2F chunk c = ks*256 + ot*64 + l           (ks<8, ot<4)        <- b_w2[(ot*16+(l&15))*256 + ks*32+(l>>4)*8]
__global__ __launch_bounds__(256) void k_prep(
    const float* __restrict__ w_w2, const float* __restrict__ w_w1,
    const float* __restrict__ b_w1, const float* __restrict__ b_w2,
    unsigned short* __restrict__ W2F, unsigned short* __restrict__ W1F,
    unsigned short* __restrict__ BW2F) {
  int t = blockIdx.x * 256 + threadIdx.x;
  const float* src; unsigned short* dst;
  if (t < 131072) {
    int c = t, i = c >> 11, ks = (c >> 8) & 7, ot = (c >> 6) & 3, l = c & 63;
    src = w_w2 + (i * 64 + ot * 16 + (l & 15)) * 256 + ks * 32 + ((l >> 4) * 8);
    dst = W2F + c * 8;
  } else if (t < 139264) {
    int c = t - 131072, ks = c >> 11, nt = (c >> 6) & 31, l = c & 63;
    int n = nt * 16 + (l & 15), k0 = ks * 32 + ((l >> 4) * 8);
    src = (n < 256) ? (w_w1 + n * 128 + k0) : (b_w1 + (n - 256) * 128 + k0);
    dst = W1F + c * 8;
  } else if (t < 141312) {
    int c = t - 139264, ks = c >> 8, ot = (c >> 6) & 3, l = c & 63;
    src = b_w2 + (ot * 16 + (l & 15)) * 256 + ks * 32 + ((l >> 4) * 8);
    dst = BW2F + c * 8;
  } else return;
  float4 f0 = *(const float4*)src;
  float4 f1 = *(const float4*)(src + 4);
  *(s16x8*)dst = cvt8(f0, f1);
}

// ---------------- K1: hypernets via MFMA -> Hcat [16384][512] bf16 ----------------
// H[m][n] = tanh( sum_k emb[m][k] * W1T[k][n] + bias[n] ), n<256: w-net, n>=256: b-net.
// grid 512: bid>>1 = m-block (64 rows), bid&1 = n-half (4 of 8 n-chunks). 4 waves split m (16 each).
__global__ __launch_bounds__(256) void k_hyper_mfma(
    const float* __restrict__ emb, const float* __restrict__ w_b1,
    const float* __restrict__ b_b1, const unsigned short* __restrict__ W1F,
    unsigned short* __restrict__ Hcat) {
  int bid = blockIdx.x, mb = bid >> 1, nh = bid & 1;
  int t = threadIdx.x, l = t & 63, w = t >> 6;
  int m0 = mb * 64;
  int mrow = m0 + w * 16 + (l & 15);
  // A frags: emb row, fp32 -> bf16 in-register. 4 k-steps of 32.
  s16x8 a[4];
  #pragma unroll
  for (int ks = 0; ks < 4; ++ks) {
    const float* p = emb + mrow * 128 + ks * 32 + ((l >> 4) * 8);
    a[ks] = cvt8(*(const float4*)p, *(const float4*)(p + 4));
  }
  #pragma unroll
  for (int j = 0; j < 4; ++j) {
    int nc = nh * 4 + j;  // n-chunk of 64
    f32x4 acc[4] = {{0,0,0,0},{0,0,0,0},{0,0,0,0},{0,0,0,0}};
    #pragma unroll
    for (int ks = 0; ks < 4; ++ks)
      #pragma unroll
      for (int ot = 0; ot < 4; ++ot) {
        s16x8 b = *(const s16x8*)(W1F + ((ks * 32 + nc * 4 + ot) * 64 + l) * 8);
        acc[ot] = __builtin_amdgcn_mfma_f32_16x16x32_bf16(a[ks], b, acc[ot], 0, 0, 0);
      }
    #pragma unroll
    for (int ot = 0; ot < 4; ++ot) {
      int n = nc * 64 + ot * 16 + (l & 15);
      float bias = (n < 256) ? w_b1[n] : b_b1[n - 256];
      #pragma unroll
      for (int r = 0; r < 4; ++r) {  // C/D: row = (l>>4)*4 + r, col = l&15
        int m = m0 + w * 16 + ((l >> 4) * 4) + r;
        Hcat[m * 512 + n] = f2bf(tanhf(acc[ot][r] + bias));
      }
    }
  }
}

// ---------------- K2: main fused MFMA GEMM + exp-contraction + sum-exp ----------------
// grid 512: bid>>1 = m-block (64 rows), bid&1 = i-half (32 i's). 4 waves split m (16 rows each).
// Wave tile [16m x 64o] per i: 4 o-tiles x 8 k-steps of 16x16x32 MFMA.
// A frags (Hw rows, bf16) loaded ONCE from global into 32 VGPRs — reused for all 32 i.
// B frags stream from pre-swizzled W2F (identical addresses across the 4 waves -> L1).
// Epilogue per i: g = C + w_b2; outa += input*exp(g); se += exp(g)*exp(logj). No max-tracking
// (|w1|<~0.2, logj<~5.5 -> sum < 2e4, fp32-safe). Partials to P; k_combine finishes.
__global__ __launch_bounds__(256) void k_main_mfma(
    const float* __restrict__ input, const float* __restrict__ logj,
    const float* __restrict__ w_b2, const float* __restrict__ b_b2,
    const unsigned short* __restrict__ W2F, const unsigned short* __restrict__ BW2F,
    const unsigned short* __restrict__ Hcat, float* __restrict__ P) {
  __shared__ float in_l[32 * 64];   // [i_local][m_local]
  __shared__ float elj[32 * 64];    // exp(logj), same layout
  int bid = blockIdx.x, mb = bid >> 1, half = bid & 1;
  int m0 = mb * 64, i0 = half * 32;
  int t = threadIdx.x, l = t & 63, w = t >> 6;

  // stage input / exp(logj): lane = m_local (broadcast-friendly reads later)
  #pragma unroll
  for (int ii = 0; ii < 8; ++ii) {
    int il = w * 8 + ii;
    in_l[il * 64 + l] = input[(m0 + l) * 64 + i0 + il];
    elj[il * 64 + l] = __expf(logj[(m0 + l) * 64 + i0 + il]);
  }

  int mrow = m0 + w * 16 + (l & 15);
  // A frags for Hw (cols 0..255 of Hcat): 8 k-steps, kept in registers for the whole kernel.
  s16x8 aw[8];
  #pragma unroll
  for (int ks = 0; ks < 8; ++ks)
    aw[ks] = *(const s16x8*)(Hcat + mrow * 512 + ks * 32 + ((l >> 4) * 8));

  float outa[4][4], se[4][4];  // [r][ot]
  #pragma unroll
  for (int r = 0; r < 4; ++r)
    #pragma unroll
    for (int ot = 0; ot < 4; ++ot) { outa[r][ot] = 0.f; se[r][ot] = 0.f; }

  if (half == 0) {  // b1 = Hb @ b_w2^T + b_b2 folded into outa (block-uniform branch)
    s16x8 ab[8];
    #pragma unroll
    for (int ks = 0; ks < 8; ++ks)
      ab[ks] = *(const s16x8*)(Hcat + mrow * 512 + 256 + ks * 32 + ((l >> 4) * 8));
    f32x4 acc[4] = {{0,0,0,0},{0,0,0,0},{0,0,0,0},{0,0,0,0}};
    #pragma unroll
    for (int ks = 0; ks < 8; ++ks)
      #pragma unroll
      for (int ot = 0; ot < 4; ++ot) {
        s16x8 b = *(const s16x8*)(BW2F + ((ks * 4 + ot) * 64 + l) * 8);
        acc[ot] = __builtin_amdgcn_mfma_f32_16x16x32_bf16(ab[ks], b, acc[ot], 0, 0, 0);
      }
    #pragma unroll
    for (int ot = 0; ot < 4; ++ot) {
      float bb = b_b2[ot * 16 + (l & 15)];
      #pragma unroll
      for (int r = 0; r < 4; ++r) outa[r][ot] = acc[ot][r] + bb;
    }
  }
  __syncthreads();

  for (int il = 0; il < 32; ++il) {
    int i = i0 + il;
    const unsigned short* Bi = W2F + i * 16384;  // 32 KB slice for this i
    f32x4 acc[4] = {{0,0,0,0},{0,0,0,0},{0,0,0,0},{0,0,0,0}};
    #pragma unroll
    for (int ks = 0; ks < 8; ++ks)
      #pragma unroll
      for (int ot = 0; ot < 4; ++ot) {
        s16x8 b = *(const s16x8*)(Bi + (ks * 4 + ot) * 512 + l * 8);
        acc[ot] = __builtin_amdgcn_mfma_f32_16x16x32_bf16(aw[ks], b, acc[ot], 0, 0, 0);
      }
    float xin[4], el[4];
    #pragma unroll
    for (int r = 0; r < 4; ++r) {
      int midx = w * 16 + ((l >> 4) * 4) + r;  // D row mapping
      xin[r] = in_l[il * 64 + midx];
      el[r] = elj[il * 64 + midx];
    }
    #pragma unroll
    for (int ot = 0; ot < 4; ++ot) {
      float wb = w_b2[i * 64 + ot * 16 + (l & 15)];
      #pragma unroll
      for (int r = 0; r < 4; ++r) {
        float e1 = __expf(acc[ot][r] + wb);
        outa[r][ot] = fmaf(xin[r], e1, outa[r][ot]);
        se[r][ot] = fmaf(e1, el[r], se[r][ot]);
      }
    }
  }

  // write partials: P = [outa_h0 | outa_h1 | se_h0 | se_h1], each 1M floats
  #pragma unroll
  for (int ot = 0; ot < 4; ++ot)
    #pragma unroll
    for (int r = 0; r < 4; ++r) {
      int m = m0 + w * 16 + ((l >> 4) * 4) + r;
      int o = ot * 16 + (l & 15);
      P[half * 1048576 + m * 64 + o] = outa[r][ot];
      P[2097152 + half * 1048576 + m * 64 + o] = se[r][ot];
    }
}

// ---------------- K3: combine halves, final log ----------------
__global__ __launch_bounds__(256) void k_combine(const float* __restrict__ P,
                                                 float* __restrict__ out) {
  int idx = (blockIdx.x * 256 + threadIdx.x) * 4;
  float4 a = *(const float4*)(P + idx);
  float4 b = *(const float4*)(P + 1048576 + idx);
  float4 c = *(const float4*)(P + 2097152 + idx);
  float4 d = *(const float4*)(P + 3145728 + idx);
  float4 o1, o2;
  o1.x = a.x + b.x; o1.y = a.y + b.y; o1.z = a.z + b.z; o1.w = a.w + b.w;
  o2.x = __logf(c.x + d.x); o2.y = __logf(c.y + d.y);
  o2.z = __logf(c.z + d.z); o2.w = __logf(c.w + d.w);
  *(float4*)(out + idx) = o1;
  *(float4*)(out + 1048576 + idx) = o2;
}

extern "C" void kernel_launch(void* const* d_in, const int* in_sizes, int n_in,
                              void* d_out, int out_size, void* d_ws, size_t ws_size,
                              hipStream_t stream) {
  const float* input = (const float*)d_in[0];
  const float* w_emb = (const float*)d_in[1];
  const float* logj  = (const float*)d_in[2];
  const float* w_w1  = (const float*)d_in[3];
  const float* w_b1  = (const float*)d_in[4];
  const float* w_w2  = (const float*)d_in[5];
  const float* w_b2  = (const float*)d_in[6];
  const float* b_w1  = (const float*)d_in[7];
  const float* b_b1  = (const float*)d_in[8];
  const float* b_w2  = (const float*)d_in[9];
  const float* b_b2  = (const float*)d_in[10];
  float* out = (float*)d_out;

  char* wsb = (char*)d_ws;
  unsigned short* W2F  = (unsigned short*)(wsb);
  unsigned short* W1F  = (unsigned short*)(wsb + 2097152);
  unsigned short* BW2F = (unsigned short*)(wsb + 2228224);
  unsigned short* Hcat = (unsigned short*)(wsb + 2260992);
  float*          P    = (float*)(wsb + 19038208);

  hipLaunchKernelGGL(k_prep, dim3(552), dim3(256), 0, stream,
                     w_w2, w_w1, b_w1, b_w2, W2F, W1F, BW2F);
  hipLaunchKernelGGL(k_hyper_mfma, dim3(512), dim3(256), 0, stream,
                     w_emb, w_b1, b_b1, W1F, Hcat);
  hipLaunchKernelGGL(k_main_mfma, dim3(512), dim3(256), 0, stream,
                     input, logj, w_b2, b_b2, W2F, BW2F, Hcat, P);
  hipLaunchKernelGGL(k_combine, dim3(1024), dim3(256), 0, stream, P, out);
}

// Round 3
// 173.635 us; speedup vs baseline: 9.3156x; 1.3805x over previous
//
#include <hip/hip_runtime.h>
#include <math.h>

// BNAF layer, fused MFMA pipeline. B=256, W=64, I=O=64, W_IN=128. M = 16384.
// Main GEMM: C[m, i*64+o] = Hw[16384,256] @ W2T[256,4096] (34.4 GFLOP bf16 MFMA),
// hypernets recomputed per block, B streamed via global_load_lds double-buffer.
// d_out: [output (1M) | logj_out (1M)] fp32.
//
// ws (bytes): W2F @0 (2,097,152) | W1F @2,097,152 (131,072) | BW2F @2,228,224 (32,768)
//             P @2,260,992 (33,554,432: outa[4 parts][1M] then se[4 parts][1M])
// total 35,815,424 B (same as R2, proven to fit).

typedef __attribute__((ext_vector_type(8))) short s16x8;   // 8 bf16 = 4 VGPR
typedef __attribute__((ext_vector_type(4))) float f32x4;   // MFMA C/D frag

__device__ inline unsigned short f2bf(float f) {
  unsigned int u = __float_as_uint(f);
  u += 0x7fffu + ((u >> 16) & 1u);
  return (unsigned short)(u >> 16);
}
__device__ inline float bf2f(unsigned short u) {
  return __uint_as_float(((unsigned int)u) << 16);
}
__device__ inline s16x8 cvt8(float4 a, float4 b) {
  s16x8 v;
  v[0] = (short)f2bf(a.x); v[1] = (short)f2bf(a.y); v[2] = (short)f2bf(a.z); v[3] = (short)f2bf(a.w);
  v[4] = (short)f2bf(b.x); v[5] = (short)f2bf(b.y); v[6] = (short)f2bf(b.z); v[7] = (short)f2bf(b.w);
  return v;
}

// async global(16B/lane) -> LDS (wave-uniform base + lane*16)
__device__ inline void stage16(const unsigned short* gsrc, char* ldst) {
  __builtin_amdgcn_global_load_lds(
      (const __attribute__((address_space(1))) unsigned int*)gsrc,
      (__attribute__((address_space(3))) unsigned int*)ldst, 16, 0, 0);
}

// ---------------- K0: pre-swizzle weights into MFMA B-frag layouts (bf16) ----------------
// 16x16x32 B frag: lane l holds n = l&15, k = (l>>4)*8 + e (16B/lane, frag = 1KB contiguous).
__global__ __launch_bounds__(256) void k_prep(
    const float* __restrict__ w_w2, const float* __restrict__ w_w1,
    const float* __restrict__ b_w1, const float* __restrict__ b_w2,
    unsigned short* __restrict__ W2F, unsigned short* __restrict__ W1F,
    unsigned short* __restrict__ BW2F) {
  int t = blockIdx.x * 256 + threadIdx.x;
  const float* src; unsigned short* dst;
  if (t < 131072) {            // W2F: chunk c = i*2048 + ks*256 + ot*64 + l
    int c = t, i = c >> 11, ks = (c >> 8) & 7, ot = (c >> 6) & 3, l = c & 63;
    src = w_w2 + (size_t)(i * 64 + ot * 16 + (l & 15)) * 256 + ks * 32 + ((l >> 4) * 8);
    dst = W2F + (size_t)c * 8;
  } else if (t < 139264) {     // W1F: c = ks*2048 + nt*64 + l  (nt<32 over concat(w,b) nets)
    int c = t - 131072, ks = c >> 11, nt = (c >> 6) & 31, l = c & 63;
    int n = nt * 16 + (l & 15), k0 = ks * 32 + ((l >> 4) * 8);
    src = (n < 256) ? (w_w1 + (size_t)n * 128 + k0) : (b_w1 + (size_t)(n - 256) * 128 + k0);
    dst = W1F + (size_t)c * 8;
  } else if (t < 141312) {     // BW2F: c = ks*256 + ot*64 + l
    int c = t - 139264, ks = c >> 8, ot = (c >> 6) & 3, l = c & 63;
    src = b_w2 + (size_t)(ot * 16 + (l & 15)) * 256 + ks * 32 + ((l >> 4) * 8);
    dst = BW2F + (size_t)c * 8;
  } else return;
  float4 f0 = *(const float4*)src;
  float4 f1 = *(const float4*)(src + 4);
  *(s16x8*)dst = cvt8(f0, f1);
}

// ---------------- K1: fused hypernet + main GEMM + exp-contraction + sum-exp ----------------
// grid 512 = mb(128 rows of m: 4 waves x 32 rows) x iq(4: 16 i each). 256 threads.
// LDS: Bbuf[2][32KB] double-buffer (also reused pre-loop as per-wave H bounce, 16KB/wave),
//      in_lds [128][16] f32 (8KB), el_lds [128][16] bf16 (4KB). Total 76KB -> 2 blocks/CU.
__global__ __launch_bounds__(256, 2) void k_fused(
    const float* __restrict__ input, const float* __restrict__ logj,
    const float* __restrict__ emb,
    const float* __restrict__ w_b1, const float* __restrict__ b_b1,
    const float* __restrict__ w_b2, const float* __restrict__ b_b2,
    const unsigned short* __restrict__ W1F, const unsigned short* __restrict__ W2F,
    const unsigned short* __restrict__ BW2F, float* __restrict__ P) {
  __shared__ __align__(16) char smem[77824];
  float* in_lds = (float*)(smem + 65536);
  unsigned short* el_lds = (unsigned short*)(smem + 73728);

  const int t = threadIdx.x;
  const int l = t & 63, lo = t & 15, hi = (t >> 4) & 3;
  const int w = t >> 6;
  const int wu = __builtin_amdgcn_readfirstlane(w);
  const int bid = blockIdx.x;
  const int mb = bid >> 2, iq = bid & 3;
  const int m0 = mb * 128, i0 = iq * 16;

  // ---- stage input / exp(logj) ----
  {
    int row = t >> 1, ilb = (t & 1) * 8;
    const float* ip = input + (size_t)(m0 + row) * 64 + i0 + ilb;
    const float* lp = logj + (size_t)(m0 + row) * 64 + i0 + ilb;
    float4 v0 = *(const float4*)ip, v1 = *(const float4*)(ip + 4);
    *(float4*)(in_lds + row * 16 + ilb) = v0;
    *(float4*)(in_lds + row * 16 + ilb + 4) = v1;
    float4 g0 = *(const float4*)lp, g1 = *(const float4*)(lp + 4);
    float lj[8] = {g0.x, g0.y, g0.z, g0.w, g1.x, g1.y, g1.z, g1.w};
    #pragma unroll
    for (int j = 0; j < 8; ++j) el_lds[row * 16 + ilb + j] = f2bf(__expf(lj[j]));
  }

  // ---- emb A-frags (2 m-tiles x 4 k-steps) ----
  s16x8 ae[2][4];
  #pragma unroll
  for (int mt = 0; mt < 2; ++mt)
    #pragma unroll
    for (int ks = 0; ks < 4; ++ks) {
      const float* p = emb + (size_t)(m0 + w * 32 + mt * 16 + lo) * 128 + ks * 32 + hi * 8;
      ae[mt][ks] = cvt8(*(const float4*)p, *(const float4*)(p + 4));
    }

  char* Hbase = smem + wu * 16384;  // per-wave H bounce region [32 rows][256 cols] bf16, XOR-swizzled

  float outa[2][4][4], se[2][4][4];
  #pragma unroll
  for (int mt = 0; mt < 2; ++mt)
    #pragma unroll
    for (int ot = 0; ot < 4; ++ot)
      #pragma unroll
      for (int r = 0; r < 4; ++r) { outa[mt][ot][r] = 0.f; se[mt][ot][r] = 0.f; }

  if (iq == 0) {  // b-net + b1 fold (block-uniform branch)
    #pragma unroll
    for (int nt = 0; nt < 16; ++nt) {
      f32x4 a2[2] = {{0,0,0,0},{0,0,0,0}};
      #pragma unroll
      for (int ks = 0; ks < 4; ++ks) {
        s16x8 b = *(const s16x8*)(W1F + ((size_t)((ks * 32 + 16 + nt) * 64 + l)) * 8);
        a2[0] = __builtin_amdgcn_mfma_f32_16x16x32_bf16(ae[0][ks], b, a2[0], 0, 0, 0);
        a2[1] = __builtin_amdgcn_mfma_f32_16x16x32_bf16(ae[1][ks], b, a2[1], 0, 0, 0);
      }
      float bias = b_b1[nt * 16 + lo];
      #pragma unroll
      for (int mt = 0; mt < 2; ++mt)
        #pragma unroll
        for (int r = 0; r < 4; ++r) {
          int row = mt * 16 + hi * 4 + r;
          int cb = (nt * 16 + lo) * 2;
          *(unsigned short*)(Hbase + row * 512 + (cb ^ ((row & 7) << 4))) =
              f2bf(tanhf(a2[mt][r] + bias));
        }
    }
    __syncthreads();
    s16x8 ab[2][8];
    #pragma unroll
    for (int mt = 0; mt < 2; ++mt)
      #pragma unroll
      for (int ks = 0; ks < 8; ++ks) {
        int row = mt * 16 + lo;
        int cb = (ks * 32 + hi * 8) * 2;
        ab[mt][ks] = *(const s16x8*)(Hbase + row * 512 + (cb ^ ((row & 7) << 4)));
      }
    f32x4 accb[2][4] = {{{0,0,0,0},{0,0,0,0},{0,0,0,0},{0,0,0,0}},
                        {{0,0,0,0},{0,0,0,0},{0,0,0,0},{0,0,0,0}}};
    #pragma unroll
    for (int ks = 0; ks < 8; ++ks)
      #pragma unroll
      for (int ot = 0; ot < 4; ++ot) {
        s16x8 b = *(const s16x8*)(BW2F + ((size_t)((ks * 4 + ot) * 64 + l)) * 8);
        accb[0][ot] = __builtin_amdgcn_mfma_f32_16x16x32_bf16(ab[0][ks], b, accb[0][ot], 0, 0, 0);
        accb[1][ot] = __builtin_amdgcn_mfma_f32_16x16x32_bf16(ab[1][ks], b, accb[1][ot], 0, 0, 0);
      }
    #pragma unroll
    for (int mt = 0; mt < 2; ++mt)
      #pragma unroll
      for (int ot = 0; ot < 4; ++ot) {
        float bb = b_b2[ot * 16 + lo];
        #pragma unroll
        for (int r = 0; r < 4; ++r) outa[mt][ot][r] = accb[mt][ot][r] + bb;
      }
  }
  __syncthreads();  // ab reads done before Hw overwrites the region

  // w-net -> Hbase
  #pragma unroll
  for (int nt = 0; nt < 16; ++nt) {
    f32x4 a2[2] = {{0,0,0,0},{0,0,0,0}};
    #pragma unroll
    for (int ks = 0; ks < 4; ++ks) {
      s16x8 b = *(const s16x8*)(W1F + ((size_t)((ks * 32 + nt) * 64 + l)) * 8);
      a2[0] = __builtin_amdgcn_mfma_f32_16x16x32_bf16(ae[0][ks], b, a2[0], 0, 0, 0);
      a2[1] = __builtin_amdgcn_mfma_f32_16x16x32_bf16(ae[1][ks], b, a2[1], 0, 0, 0);
    }
    float bias = w_b1[nt * 16 + lo];
    #pragma unroll
    for (int mt = 0; mt < 2; ++mt)
      #pragma unroll
      for (int r = 0; r < 4; ++r) {
        int row = mt * 16 + hi * 4 + r;
        int cb = (nt * 16 + lo) * 2;
        *(unsigned short*)(Hbase + row * 512 + (cb ^ ((row & 7) << 4))) =
            f2bf(tanhf(a2[mt][r] + bias));
      }
  }
  __syncthreads();
  s16x8 aw[2][8];  // A-frags for main GEMM, live across whole i-loop (64 VGPR)
  #pragma unroll
  for (int mt = 0; mt < 2; ++mt)
    #pragma unroll
    for (int ks = 0; ks < 8; ++ks) {
      int row = mt * 16 + lo;
      int cb = (ks * 32 + hi * 8) * 2;
      aw[mt][ks] = *(const s16x8*)(Hbase + row * 512 + (cb ^ ((row & 7) << 4)));
    }
  __syncthreads();  // H reads done before B staging overwrites Bbuf

  // ---- main 2-phase pipeline over 16 i ----
  // stage chunk c=(ks*4+ot): wave wu stages c = wu*8+j, j<8; LDS linear frag layout.
  {
    const unsigned short* Bi = W2F + (size_t)i0 * 16384;
    #pragma unroll
    for (int j = 0; j < 8; ++j) {
      int c = wu * 8 + j;
      stage16(Bi + (size_t)c * 512 + l * 8, smem + c * 1024);
    }
  }
  __syncthreads();

  for (int il = 0; il < 16; ++il) {
    const int cur = il & 1;
    if (il < 15) {  // stage next i into other buffer (flies during compute)
      const unsigned short* Bi = W2F + (size_t)(i0 + il + 1) * 16384;
      #pragma unroll
      for (int j = 0; j < 8; ++j) {
        int c = wu * 8 + j;
        stage16(Bi + (size_t)c * 512 + l * 8, smem + (cur ^ 1) * 32768 + c * 1024);
      }
    }
    const char* bb = smem + cur * 32768;
    f32x4 acc[2][4] = {{{0,0,0,0},{0,0,0,0},{0,0,0,0},{0,0,0,0}},
                       {{0,0,0,0},{0,0,0,0},{0,0,0,0},{0,0,0,0}}};
    #pragma unroll
    for (int ks = 0; ks < 8; ++ks)
      #pragma unroll
      for (int ot = 0; ot < 4; ++ot) {
        s16x8 b = *(const s16x8*)(bb + (ks * 4 + ot) * 1024 + l * 16);
        acc[0][ot] = __builtin_amdgcn_mfma_f32_16x16x32_bf16(aw[0][ks], b, acc[0][ot], 0, 0, 0);
        acc[1][ot] = __builtin_amdgcn_mfma_f32_16x16x32_bf16(aw[1][ks], b, acc[1][ot], 0, 0, 0);
      }
    const int i = i0 + il;
    float wb[4];
    #pragma unroll
    for (int ot = 0; ot < 4; ++ot) wb[ot] = w_b2[(size_t)i * 64 + ot * 16 + lo];
    #pragma unroll
    for (int mt = 0; mt < 2; ++mt)
      #pragma unroll
      for (int r = 0; r < 4; ++r) {
        int rl = w * 32 + mt * 16 + hi * 4 + r;
        float xin = in_lds[rl * 16 + il];
        float el = bf2f(el_lds[rl * 16 + il]);
        #pragma unroll
        for (int ot = 0; ot < 4; ++ot) {
          float e1 = __expf(acc[mt][ot][r] + wb[ot]);
          outa[mt][ot][r] = fmaf(xin, e1, outa[mt][ot][r]);
          se[mt][ot][r] = fmaf(el, e1, se[mt][ot][r]);
        }
      }
    __syncthreads();  // drains stage(il+1) vmcnt + protects buffer reuse
  }

  // ---- partial stores: P[iq][m][o] (outa), P[4M + iq*1M + ...] (se) ----
  #pragma unroll
  for (int mt = 0; mt < 2; ++mt)
    #pragma unroll
    for (int ot = 0; ot < 4; ++ot)
      #pragma unroll
      for (int r = 0; r < 4; ++r) {
        int m = m0 + w * 32 + mt * 16 + hi * 4 + r;
        int o = ot * 16 + lo;
        P[(size_t)iq * 1048576 + (size_t)m * 64 + o] = outa[mt][ot][r];
        P[4194304 + (size_t)iq * 1048576 + (size_t)m * 64 + o] = se[mt][ot][r];
      }
}

// ---------------- K2: combine 4 partials, final log ----------------
__global__ __launch_bounds__(256) void k_combine(const float* __restrict__ P,
                                                 float* __restrict__ out) {
  int idx = (blockIdx.x * 256 + threadIdx.x) * 4;
  float4 s = {0.f, 0.f, 0.f, 0.f}, e = {0.f, 0.f, 0.f, 0.f};
  #pragma unroll
  for (int p = 0; p < 4; ++p) {
    float4 a = *(const float4*)(P + (size_t)p * 1048576 + idx);
    s.x += a.x; s.y += a.y; s.z += a.z; s.w += a.w;
    float4 b = *(const float4*)(P + 4194304 + (size_t)p * 1048576 + idx);
    e.x += b.x; e.y += b.y; e.z += b.z; e.w += b.w;
  }
  *(float4*)(out + idx) = s;
  float4 lg;
  lg.x = __logf(e.x); lg.y = __logf(e.y); lg.z = __logf(e.z); lg.w = __logf(e.w);
  *(float4*)(out + 1048576 + idx) = lg;
}

extern "C" void kernel_launch(void* const* d_in, const int* in_sizes, int n_in,
                              void* d_out, int out_size, void* d_ws, size_t ws_size,
                              hipStream_t stream) {
  const float* input = (const float*)d_in[0];
  const float* w_emb = (const float*)d_in[1];
  const float* logj  = (const float*)d_in[2];
  const float* w_w1  = (const float*)d_in[3];
  const float* w_b1  = (const float*)d_in[4];
  const float* w_w2  = (const float*)d_in[5];
  const float* w_b2  = (const float*)d_in[6];
  const float* b_w1  = (const float*)d_in[7];
  const float* b_b1  = (const float*)d_in[8];
  const float* b_w2  = (const float*)d_in[9];
  const float* b_b2  = (const float*)d_in[10];
  float* out = (float*)d_out;

  char* wsb = (char*)d_ws;
  unsigned short* W2F  = (unsigned short*)(wsb);
  unsigned short* W1F  = (unsigned short*)(wsb + 2097152);
  unsigned short* BW2F = (unsigned short*)(wsb + 2228224);
  float*          P    = (float*)(wsb + 2260992);

  hipLaunchKernelGGL(k_prep, dim3(552), dim3(256), 0, stream,
                     w_w2, w_w1, b_w1, b_w2, W2F, W1F, BW2F);
  hipLaunchKernelGGL(k_fused, dim3(512), dim3(256), 0, stream,
                     input, logj, w_emb, w_b1, b_b1, w_b2, b_b2, W1F, W2F, BW2F, P);
  hipLaunchKernelGGL(k_combine, dim3(1024), dim3(256), 0, stream, P, out);
}